// Round 5
// baseline (497.837 us; speedup 1.0000x reference)
//
#include <hip/hip_runtime.h>

// HybridAttention (fp32 I/O, bf16 MFMA internals):
// x -> cast bf16 -> QKV proj (MFMA GEMM, fused N=3072, split-store Q/K/V bf16)
// -> fused {G=Q K^T tile + diagonal-sum} (G never materialized) -> bandpass
// filter (g = irfft of band mask) -> top-6 + softmax -> context = weighted V
// row-gather (bf16) -> out GEMM (+bias+residual, fp32 into d_out) -> LayerNorm
// in-place on d_out. fp32 accumulate everywhere. ws need = 142,741,952 B.
//
// R11 == R10 resubmission (round 4 failed on container acquisition; kernel
// never reached hardware; hang-audit found no defect: uniform barriers,
// vmcnt ledger closes, WAR slots all behind exit barriers, ~217 VGPR < 256).
//
// R10: faithful m201 8-phase template. R7 (kk-phases) and R9 (rotated pipeline)
// both plateau at 845-905 TF vs the hardware-verified 1563 TF of the m201
// schedule; this round removes every remaining deviation:
//  - 2 K-tiles per loop iteration, buffer index is a COMPILE-TIME constant
//  - phase = one C-quadrant (64x32 of the wave's 128x64) x K=64 = 16 MFMA
//  - reads 12/4/8/0 per phase; A-frags reused across n-quadrants, B-frags
//    held across m-quadrants (64 operand VGPRs total)
//  - one {entry bar; lgkmcnt(0)} + {exit bar} pair per phase; counted vmcnt
//    ONLY at phases 4 (vmcnt 4) and 8 (vmcnt 8), never 0 in steady state
//  - stage slots after each half's last-reader exit barrier:
//    ph3:B0(b0) ph4:B1(b0) ph5:A0(b0) ph6:A1(b0) ph7:B0(b1) ph8:B1+A0+A1(b1)
//    prologue stages tiles 0+1 (16 loads) + vmcnt(8); tail iter stage-free.
// XOR-swizzled LDS as in R6-R9 (0 bank conflicts measured).

typedef unsigned short u16;
typedef unsigned int   u32;
typedef __attribute__((ext_vector_type(8))) __bf16 bf16x8;
typedef __attribute__((ext_vector_type(4))) float  floatx4;

#define HIDn 1024

__device__ __forceinline__ u16 f2b(float f){ u32 i = __float_as_uint(f); return (u16)((i + 0x7fffu + ((i>>16)&1u)) >> 16); }

__device__ __forceinline__ void gl_lds16(const u16* g, u16* l){
  __builtin_amdgcn_global_load_lds((__attribute__((address_space(1))) const void*)g,
                                   (__attribute__((address_space(3))) void*)l, 16, 0, 0);
}

__device__ __forceinline__ void bar(){
  asm volatile("" ::: "memory");
  __builtin_amdgcn_s_barrier();
  asm volatile("" ::: "memory");
}
__device__ __forceinline__ void lgkm0(){
  asm volatile("s_waitcnt lgkmcnt(0)" ::: "memory");
  __builtin_amdgcn_sched_barrier(0);
}

// ---------------------------------------------------------------- ws guard
__global__ void fill_kernel(float* __restrict__ out, float v, int n)
{
  const int i = blockIdx.x*blockDim.x + threadIdx.x;
  if (i < n) out[i] = v;
}

// ---------------------------------------------------------------- cast x -> bf16
__global__ __launch_bounds__(256)
void cast_kernel(const float* __restrict__ x, u16* __restrict__ xb)
{
  const int i = blockIdx.x*256 + threadIdx.x;   // 2,097,152 threads x 8 floats
  const float4* xp = (const float4*)x;
  const float4 a = xp[2*i], b = xp[2*i+1];
  uint4 o;
  o.x = (u32)f2b(a.x) | ((u32)f2b(a.y)<<16);
  o.y = (u32)f2b(a.z) | ((u32)f2b(a.w)<<16);
  o.z = (u32)f2b(b.x) | ((u32)f2b(b.y)<<16);
  o.w = (u32)f2b(b.z) | ((u32)f2b(b.w)<<16);
  ((uint4*)xb)[i] = o;
}

// ---------------------------------------------------------------- transpose+cast
// WqkvT (3072 x 1024, n-major, bf16) and WdT (1024 x 1024, bf16) from fp32 W.
__global__ __launch_bounds__(1024)
void transpose_kernel(const float* __restrict__ Wq, const float* __restrict__ Wk,
                      const float* __restrict__ Wv, const float* __restrict__ Wd,
                      u16* __restrict__ WqkvT, u16* __restrict__ WdT)
{
  __shared__ float tile[32][33];
  const int mat = blockIdx.z;
  const float* W = (mat==0)?Wq:(mat==1)?Wk:(mat==2)?Wv:Wd;
  const int k = blockIdx.y*32 + threadIdx.y;
  const int n = blockIdx.x*32 + threadIdx.x;
  tile[threadIdx.y][threadIdx.x] = W[(long)k*HIDn + n];
  __syncthreads();
  const int on = blockIdx.x*32 + threadIdx.y;
  const int ok = blockIdx.y*32 + threadIdx.x;
  const u16 val = f2b(tile[threadIdx.x][threadIdx.y]);
  if (mat < 3) WqkvT[(long)(mat*HIDn + on)*HIDn + ok] = val;
  else         WdT[(long)on*HIDn + ok] = val;
}

// ---------------------------------------------------------------- gf + zero c
// g[d] = (2*sum_{f=205..511} cos(2 pi f d/1024) + (-1)^d) / 1024^2
__global__ __launch_bounds__(1024)
void gf_kernel(float* __restrict__ gf, float* __restrict__ c)
{
  const int d = threadIdx.x;
  float s = 0.f;
  for (int f = 205; f < 512; ++f){
    int p = (f*d) & 1023;
    s += cosf(6.283185307179586f * (float)p * (1.0f/1024.0f));
  }
  gf[d] = (2.f*s + ((d & 1) ? -1.f : 1.f)) * (1.0f/1048576.0f);
  #pragma unroll
  for (int b = 0; b < 16; ++b) c[b*1024 + d] = 0.f;
}

// ---------------------------------------------------------------- MFMA GEMM
// C(M x N) = A(M x K) * Bt(N x K)^T ; bf16 in, fp32 acc. 256x256 tile, 8 waves
// (2Mx4N), per-wave 128x64 (acc[8][4] 16x16x32 frags), BK=64, m201 8-phase
// schedule (see header). Requires K % 128 == 0, K >= 256.
// EPI 0: +fp32 bias (select by bx>>2), bf16 split-store to C0/o1/o2 (Q/K/V).
// EPI 2: +fp32 bias +fp32 resid, fp32 out (hidden+residual -> d_out).
// EPI 3: no C store; diagonal-sum tile into cbuf[bz*1024 + d] (atomics).
template<int EPI>
__global__ __launch_bounds__(512, 2)
void gemm_mfma(const u16* __restrict__ A, int lda, long sA,
               const u16* __restrict__ Bt, int ldb, long sB,
               void* __restrict__ C0, u16* __restrict__ o1, u16* __restrict__ o2,
               int ldc, int K,
               const float* __restrict__ b0, const float* __restrict__ b1,
               const float* __restrict__ b2, const float* __restrict__ resid,
               float* __restrict__ cbuf)
{
  __shared__ __align__(16) u16 As[2][16384];   // 2 x (256 rows x 64 k)
  __shared__ __align__(16) u16 Bs[2][16384];
  __shared__ float bins[512];

  const int bx = blockIdx.x, by = blockIdx.y, bz = blockIdx.z;
  const int tid  = threadIdx.x;
  const int wave = tid >> 6, lane = tid & 63;
  const int waveM = wave >> 2, waveN = wave & 3;
  const int qd = lane >> 4, ln = lane & 15, rl = ln & 7;
  const u16* Ab = A  + (long)bz * sA;
  const u16* Bb = Bt + (long)bz * sB;
  const int aRow0 = by * 256, bRow0 = bx * 256;
  const int nt = K >> 6;

  // staging: slot s = wave*128 + lane within a 128-row half (8 chunks/row)
  const int s0 = wave*128 + lane;
  const int r0 = s0 >> 3, r1 = r0 + 8;
  const int kc = ((s0 & 7) ^ (r0 & 7)) * 8;          // pre-swizzled source chunk
  const long aOff0 = (long)(aRow0 + r0)*lda + kc;
  const long aOff1 = (long)(aRow0 + r1)*lda + kc;
  const long bOff0 = (long)(bRow0 + r0)*ldb + kc;
  const long bOff1 = (long)(bRow0 + r1)*ldb + kc;
  const int dstW = wave*1024;                         // u16, wave-uniform

#define STAGE_A(p, h, kt) do{ \
    gl_lds16(Ab + aOff0 + (long)(h)*128*lda + (kt), &As[p][(h)*8192 + dstW]); \
    gl_lds16(Ab + aOff1 + (long)(h)*128*lda + (kt), &As[p][(h)*8192 + dstW + 512]); }while(0)
#define STAGE_B(p, h, kt) do{ \
    gl_lds16(Bb + bOff0 + (long)(h)*128*ldb + (kt), &Bs[p][(h)*8192 + dstW]); \
    gl_lds16(Bb + bOff1 + (long)(h)*128*ldb + (kt), &Bs[p][(h)*8192 + dstW + 512]); }while(0)

  if (EPI == 3) bins[tid] = 0.f;       // synced by prologue barrier

  floatx4 acc[8][4];
  const floatx4 z4 = {0.f, 0.f, 0.f, 0.f};
  #pragma unroll
  for (int i=0;i<8;++i)
    #pragma unroll
    for (int j=0;j<4;++j) acc[i][j] = z4;

  // read addressing: row R frag at u16 offset R*64 + ((chunk)^(R&7))*8
  const int aRd = (waveM*128 + ln)*64;   // + MH*4096 + mi*1024
  const int bRd = (waveN*64  + ln)*64;   // + ni*1024
  const int csw0 = ((0 + qd) ^ rl) * 8;  // kk=0 chunk
  const int csw1 = ((4 + qd) ^ rl) * 8;  // kk=1 chunk

  bf16x8 av0[4], av1[4];                 // current m-half, kk0/kk1
  bf16x8 bvA0[2], bvA1[2];               // n-half0 (ni 0,1), kk0/kk1
  bf16x8 bvB0[2], bvB1[2];               // n-half1 (ni 2,3), kk0/kk1

#define DS_AV(BUF, MH) do{ const u16* Ap_ = &As[BUF][0]; \
    _Pragma("unroll") for (int mi=0;mi<4;++mi){ \
      av0[mi] = *(const bf16x8*)(Ap_ + aRd + (MH)*4096 + mi*1024 + csw0); \
      av1[mi] = *(const bf16x8*)(Ap_ + aRd + (MH)*4096 + mi*1024 + csw1); } }while(0)
#define DS_BV(BUF, NH, d0_, d1_) do{ const u16* Bp_ = &Bs[BUF][0]; \
    _Pragma("unroll") for (int ni=0;ni<2;++ni){ \
      d0_[ni] = *(const bf16x8*)(Bp_ + bRd + ((NH)*2+ni)*1024 + csw0); \
      d1_[ni] = *(const bf16x8*)(Bp_ + bRd + ((NH)*2+ni)*1024 + csw1); } }while(0)
#define MFMAQ(MH, NH, b0_, b1_) do{ \
    __builtin_amdgcn_sched_barrier(0); \
    __builtin_amdgcn_s_setprio(1); \
    _Pragma("unroll") for (int mi=0;mi<4;++mi) \
      _Pragma("unroll") for (int ni=0;ni<2;++ni){ \
        acc[(MH)*4+mi][(NH)*2+ni] = __builtin_amdgcn_mfma_f32_16x16x32_bf16(av0[mi], b0_[ni], acc[(MH)*4+mi][(NH)*2+ni],0,0,0); \
        acc[(MH)*4+mi][(NH)*2+ni] = __builtin_amdgcn_mfma_f32_16x16x32_bf16(av1[mi], b1_[ni], acc[(MH)*4+mi][(NH)*2+ni],0,0,0); } \
    __builtin_amdgcn_s_setprio(0); \
    __builtin_amdgcn_sched_barrier(0); }while(0)

  // ---- prologue: stage tile0 -> buf0, tile1 -> buf1 (16 loads); tile0 landed
  STAGE_B(0,0,0);  STAGE_B(0,1,0);  STAGE_A(0,0,0);  STAGE_A(0,1,0);
  STAGE_B(1,0,64); STAGE_B(1,1,64); STAGE_A(1,0,64); STAGE_A(1,1,64);
  asm volatile("s_waitcnt vmcnt(8)" ::: "memory");
  bar();

  const int nIt = nt >> 1;
  for (int it = 0; it < nIt-1; ++it){
    const int k2 = (it*2+2) << 6;
    const int k3 = (it*2+3) << 6;
    // ======== tile t0 (buffer 0) ========
    // ph1 (m0,n0): 12 reads
    DS_AV(0,0); DS_BV(0,0,bvA0,bvA1);
    bar(); lgkm0(); MFMAQ(0,0,bvA0,bvA1); bar();
    // ph2 (m0,n1): 4 reads
    DS_BV(0,1,bvB0,bvB1);
    bar(); lgkm0(); MFMAQ(0,1,bvB0,bvB1); bar();
    // ph3 (m1,n0): 8 reads; stage B0(b0,t0+2) (B(b0) free since ph2-exit)
    DS_AV(0,1); STAGE_B(0,0,k2);
    bar(); lgkm0(); MFMAQ(1,0,bvA0,bvA1); bar();
    // ph4 (m1,n1): 0 reads; stage B1(b0); vmcnt(4) -> tile t1 fully landed
    STAGE_B(0,1,k2);
    asm volatile("s_waitcnt vmcnt(4)" ::: "memory");
    bar(); MFMAQ(1,1,bvB0,bvB1); bar();
    // ======== tile t1 (buffer 1) ========
    // ph5: stage A0(b0) (A(b0) free since ph3-exit)
    DS_AV(1,0); DS_BV(1,0,bvA0,bvA1); STAGE_A(0,0,k2);
    bar(); lgkm0(); MFMAQ(0,0,bvA0,bvA1); bar();
    // ph6: stage A1(b0)
    DS_BV(1,1,bvB0,bvB1); STAGE_A(0,1,k2);
    bar(); lgkm0(); MFMAQ(0,1,bvB0,bvB1); bar();
    // ph7: stage B0(b1,t1+2) (B(b1) free since ph6-exit)
    DS_AV(1,1); STAGE_B(1,0,k3);
    bar(); lgkm0(); MFMAQ(1,0,bvA0,bvA1); bar();
    // ph8: stage B1+A0+A1(b1) (A(b1) free since ph7-exit); vmcnt(8) -> b0 landed
    STAGE_B(1,1,k3); STAGE_A(1,0,k3); STAGE_A(1,1,k3);
    asm volatile("s_waitcnt vmcnt(8)" ::: "memory");
    bar(); MFMAQ(1,1,bvB0,bvB1); bar();
  }
  // ======== tail: tiles nt-2 (buf0), nt-1 (buf1), no stages ========
  DS_AV(0,0); DS_BV(0,0,bvA0,bvA1);
  bar(); lgkm0(); MFMAQ(0,0,bvA0,bvA1); bar();
  DS_BV(0,1,bvB0,bvB1);
  bar(); lgkm0(); MFMAQ(0,1,bvB0,bvB1); bar();
  DS_AV(0,1);
  bar(); lgkm0(); MFMAQ(1,0,bvA0,bvA1); bar();
  asm volatile("s_waitcnt vmcnt(0)" ::: "memory");  // drain b1 (tile nt-1)
  bar(); MFMAQ(1,1,bvB0,bvB1); bar();
  DS_AV(1,0); DS_BV(1,0,bvA0,bvA1);
  bar(); lgkm0(); MFMAQ(0,0,bvA0,bvA1); bar();
  DS_BV(1,1,bvB0,bvB1);
  bar(); lgkm0(); MFMAQ(0,1,bvB0,bvB1); bar();
  DS_AV(1,1);
  bar(); lgkm0(); MFMAQ(1,0,bvA0,bvA1); bar();
  MFMAQ(1,1,bvB0,bvB1);
#undef STAGE_A
#undef STAGE_B
#undef DS_AV
#undef DS_BV
#undef MFMAQ

  if (EPI == 3){
    // G[l][m] at frag(mi,ni) reg r lane(qd,ln):
    //   l-m = (aRow0-bRow0) + 128*waveM - 64*waveN + 16*(mi-ni) + 4*qd + r - ln
    float dsum[11][4];
    #pragma unroll
    for (int dd=0; dd<11; ++dd)
      #pragma unroll
      for (int r=0;r<4;++r) dsum[dd][r] = 0.f;
    #pragma unroll
    for (int mi=0;mi<8;++mi)
      #pragma unroll
      for (int ni=0;ni<4;++ni){
        const int dd = mi - ni + 3;
        #pragma unroll
        for (int r=0;r<4;++r) dsum[dd][r] += acc[mi][ni][r];
      }
    const int base = 255 + 128*waveM - 64*waveN + 4*qd - ln;
    #pragma unroll
    for (int dd=0; dd<11; ++dd)
      #pragma unroll
      for (int r=0;r<4;++r)
        atomicAdd(&bins[base + 16*(dd-3) + r], dsum[dd][r]);
    __syncthreads();
    if (tid < 511){
      const int d = (aRow0 - bRow0 + tid - 255) & 1023;
      atomicAdd(cbuf + bz*1024 + d, bins[tid]);
    }
    return;
  }

  // epilogue: C/D layout col = lane&15, row = (lane>>4)*4 + reg
  if (EPI == 0){
    const int which = bx >> 2;                 // 256-tile never crosses 1024
    const float* bp = (which==0) ? b0 : ((which==1) ? b1 : b2);
    u16* Cb = (which==0) ? (u16*)C0 : ((which==1) ? o1 : o2);
    const int nb = bRow0 & 1023;
    #pragma unroll
    for (int mi=0;mi<8;++mi){
      const int gm = aRow0 + waveM*128 + mi*16 + qd*4;
      #pragma unroll
      for (int ni=0;ni<4;++ni){
        const int nl = nb + waveN*64 + ni*16 + ln;
        const float bias = bp[nl];
        #pragma unroll
        for (int r=0;r<4;++r) Cb[(long)(gm+r)*ldc + nl] = f2b(acc[mi][ni][r] + bias);
      }
    }
  } else {  // EPI == 2
    float* C = (float*)C0;
    #pragma unroll
    for (int mi=0;mi<8;++mi){
      const int gm = aRow0 + waveM*128 + mi*16 + qd*4;
      #pragma unroll
      for (int ni=0;ni<4;++ni){
        const int gn = bRow0 + waveN*64 + ni*16 + ln;
        const float bias = b0[gn];
        #pragma unroll
        for (int r=0;r<4;++r)
          C[(long)(gm+r)*ldc + gn] = acc[mi][ni][r] + bias + resid[(long)(gm+r)*ldc + gn];
      }
    }
  }
}

// ---------------------------------------------------------------- filter
// mv[b,n] = sum_m c[b,m] * gf[(n-m)&1023]
__global__ __launch_bounds__(1024)
void filter_kernel(const float* __restrict__ c, const float* __restrict__ gf,
                   float* __restrict__ mv)
{
  __shared__ float carr[1024];
  __shared__ float gsh[1024];
  const int b = blockIdx.x, l = threadIdx.x;
  carr[l] = c[b*1024 + l]; gsh[l] = gf[l];
  __syncthreads();
  float o = 0.f;
  #pragma unroll 4
  for (int m = 0; m < 1024; ++m) o += carr[m] * gsh[(l - m) & 1023];
  mv[b*1024 + l] = o;
}

// ---------------------------------------------------------------- top-6 + softmax
__global__ __launch_bounds__(1024)
void topk_kernel(const float* __restrict__ mv, int* __restrict__ idxout,
                 float* __restrict__ wout)
{
  __shared__ float vals[1024];
  __shared__ float rv[1024];
  __shared__ int   ri[1024];
  __shared__ int   chosen[6];
  const int t = threadIdx.x;
  float s = 0.f;
  #pragma unroll
  for (int b = 0; b < 16; ++b) s += mv[b*1024 + t];
  vals[t] = s;
  __syncthreads();
  for (int r = 0; r < 6; ++r){
    rv[t] = vals[t]; ri[t] = t; __syncthreads();
    for (int off = 512; off > 0; off >>= 1){
      if (t < off){
        const float v2 = rv[t+off]; const int i2 = ri[t+off];
        if (v2 > rv[t] || (v2 == rv[t] && i2 < ri[t])){ rv[t] = v2; ri[t] = i2; }
      }
      __syncthreads();
    }
    if (t == 0){ chosen[r] = ri[0]; idxout[r] = ri[0]; }
    __syncthreads();
    if (t == chosen[r]) vals[t] = -3.0e38f;
    __syncthreads();
  }
  if (t < 16){
    float w[6]; float mx = -3.0e38f;
    #pragma unroll
    for (int i = 0; i < 6; ++i){ w[i] = mv[t*1024 + chosen[i]]; mx = fmaxf(mx, w[i]); }
    float sum = 0.f;
    #pragma unroll
    for (int i = 0; i < 6; ++i){ w[i] = expf(w[i] - mx); sum += w[i]; }
    #pragma unroll
    for (int i = 0; i < 6; ++i) wout[t*6 + i] = w[i] / sum;
  }
}

// ---------------------------------------------------------------- context gather
// CT[b*1024+l, :] = sum_i w[b,i] * V[b, (l+idx_i)&1023, :]   (bf16 in/out)
__global__ __launch_bounds__(256)
void context_kernel(const u16* __restrict__ Vb, const int* __restrict__ idx,
                    const float* __restrict__ w, u16* __restrict__ CT)
{
  const int row = blockIdx.x*2 + (threadIdx.x >> 7);
  const int b = row >> 10, l = row & 1023;
  const int t = threadIdx.x & 127;       // chunk of 8 channels
  float wl[6]; int id[6];
  #pragma unroll
  for (int i = 0; i < 6; ++i){ id[i] = idx[i]; wl[i] = w[b*6 + i]; }
  float acc[8] = {0,0,0,0,0,0,0,0};
  #pragma unroll
  for (int i = 0; i < 6; ++i){
    const long src = (long)b*1024 + ((l + id[i]) & 1023);
    const uint4 pk = *(const uint4*)(Vb + src*1024 + t*8);
    const float ww = wl[i];
    union{float f; u32 u;} cv;
    cv.u = pk.x<<16;          acc[0] += ww*cv.f;
    cv.u = pk.x & 0xffff0000u; acc[1] += ww*cv.f;
    cv.u = pk.y<<16;          acc[2] += ww*cv.f;
    cv.u = pk.y & 0xffff0000u; acc[3] += ww*cv.f;
    cv.u = pk.z<<16;          acc[4] += ww*cv.f;
    cv.u = pk.z & 0xffff0000u; acc[5] += ww*cv.f;
    cv.u = pk.w<<16;          acc[6] += ww*cv.f;
    cv.u = pk.w & 0xffff0000u; acc[7] += ww*cv.f;
  }
  uint4 o;
  o.x = (u32)f2b(acc[0]) | ((u32)f2b(acc[1])<<16);
  o.y = (u32)f2b(acc[2]) | ((u32)f2b(acc[3])<<16);
  o.z = (u32)f2b(acc[4]) | ((u32)f2b(acc[5])<<16);
  o.w = (u32)f2b(acc[6]) | ((u32)f2b(acc[7])<<16);
  *(uint4*)(CT + (long)row*1024 + t*8) = o;
}

// ---------------------------------------------------------------- layernorm (in-place fp32)
__global__ __launch_bounds__(256)
void ln_kernel(float* __restrict__ io, const float* __restrict__ gamma,
               const float* __restrict__ beta)
{
  __shared__ float s1[256];
  __shared__ float s2[256];
  const int row = blockIdx.x, t = threadIdx.x;
  float4 v = ((const float4*)(io + (long)row*1024))[t];
  s1[t] = v.x+v.y+v.z+v.w;
  s2[t] = v.x*v.x+v.y*v.y+v.z*v.z+v.w*v.w;
  __syncthreads();
  for (int off = 128; off > 0; off >>= 1){
    if (t < off){ s1[t] += s1[t+off]; s2[t] += s2[t+off]; }
    __syncthreads();
  }
  const float mu  = s1[0] * (1.f/1024.f);
  const float var = fmaxf(s2[0] * (1.f/1024.f) - mu*mu, 0.f);
  const float rstd = rsqrtf(var + 1e-12f);
  const float4 g  = ((const float4*)gamma)[t];
  const float4 be = ((const float4*)beta)[t];
  float4 o;
  o.x = (v.x-mu)*rstd*g.x + be.x;
  o.y = (v.y-mu)*rstd*g.y + be.y;
  o.z = (v.z-mu)*rstd*g.z + be.z;
  o.w = (v.w-mu)*rstd*g.w + be.w;
  ((float4*)(io + (long)row*1024))[t] = o;
}

// ---------------------------------------------------------------- launch
extern "C" void kernel_launch(void* const* d_in, const int* in_sizes, int n_in,
                              void* d_out, int out_size, void* d_ws, size_t ws_size,
                              hipStream_t stream)
{
  (void)in_sizes; (void)n_in;
  const float* x     = (const float*)d_in[0];
  // d_in[1] attention_mask: zeros, unused by the reference math
  const float* Wq    = (const float*)d_in[2];
  const float* bq    = (const float*)d_in[3];
  const float* Wk    = (const float*)d_in[4];
  const float* bk    = (const float*)d_in[5];
  const float* Wv    = (const float*)d_in[6];
  const float* bv    = (const float*)d_in[7];
  const float* Wd    = (const float*)d_in[8];
  const float* bd    = (const float*)d_in[9];
  const float* gamma = (const float*)d_in[10];
  const float* beta  = (const float*)d_in[11];
  float* outp = (float*)d_out;

  // ws layout (bytes), total 142,741,952:
  // xb 32M | Qb 32M | Kb 32M | Vb 32M | WqkvT 6M | WdT 2M | cbuf 64K | mv 64K | gf 4K | idx | w
  const size_t NEED = 142741952UL;
  if (ws_size < NEED){
    // guard: encode ws_size into the output so a failing absmax reveals it
    const int n = out_size/2;
    fill_kernel<<<(n+255)/256, 256, 0, stream>>>(outp, (float)ws_size, n);
    return;
  }
  char* ws = (char*)d_ws;
  u16*  xb    = (u16*)(ws);
  u16*  Qb    = (u16*)(ws + 33554432L);
  u16*  Kb    = (u16*)(ws + 67108864L);
  u16*  Vb    = (u16*)(ws + 100663296L);
  u16*  WqkvT = (u16*)(ws + 134217728L);
  u16*  WdT   = (u16*)(ws + 140509184L);
  float* cbuf = (float*)(ws + 142606336L);
  float* mv   = (float*)(ws + 142671872L);
  float* gf   = (float*)(ws + 142737408L);
  int*   idxb = (int*)  (ws + 142741504L);
  float* wsm  = (float*)(ws + 142741568L);
  u16*  CT    = Qb;   // reuse: Q's last reader is the G-gemm

  cast_kernel<<<8192, 256, 0, stream>>>(x, xb);
  transpose_kernel<<<dim3(32,32,4), dim3(32,32), 0, stream>>>(Wq, Wk, Wv, Wd, WqkvT, WdT);
  gf_kernel<<<1, 1024, 0, stream>>>(gf, cbuf);

  // Q|K|V = x @ [Wq|Wk|Wv] + bias (M=16384, N=3072, K=1024), bf16 split-store
  gemm_mfma<0><<<dim3(12,64,1), 512, 0, stream>>>(
      xb, 1024, 0L, WqkvT, 1024, 0L, Qb, Kb, Vb, 1024, 1024,
      bq, bk, bv, nullptr, nullptr);

  // c[b,d] += diag-sums of Q[b] @ K[b]^T  (batched, M=N=K=1024, G not stored)
  gemm_mfma<3><<<dim3(4,4,16), 512, 0, stream>>>(
      Qb, 1024, 1048576L, Kb, 1024, 1048576L, nullptr, nullptr, nullptr, 0, 1024,
      nullptr, nullptr, nullptr, nullptr, cbuf);

  filter_kernel<<<16, 1024, 0, stream>>>(cbuf, gf, mv);
  topk_kernel<<<1, 1024, 0, stream>>>(mv, idxb, wsm);
  context_kernel<<<8192, 256, 0, stream>>>(Vb, idxb, wsm, CT);

  // d_out = CT @ Wd + bd + x  (fp32, M=16384, N=1024, K=1024)
  gemm_mfma<2><<<dim3(4,64,1), 512, 0, stream>>>(
      CT, 1024, 0L, WdT, 1024, 0L, outp, nullptr, nullptr, 1024, 1024,
      bd, nullptr, nullptr, x, nullptr);

  ln_kernel<<<16384, 256, 0, stream>>>(outp, gamma, beta);
}

// Round 6
// 439.026 us; speedup vs baseline: 1.1340x; 1.1340x over previous
//
#include <hip/hip_runtime.h>

// HybridAttention (fp32 I/O, bf16 MFMA internals):
// x -> cast bf16 (+zero cbuf) -> QKV proj (MFMA GEMM, fused N=3072, split-store
// Q/K/V bf16) -> fused {G=Q K^T tile + diagonal-sum} (G never materialized)
// -> bandpass filter (Dirichlet closed-form gf, computed in-kernel) -> top-6 +
// softmax (wave-shuffle argmax) -> context = weighted V row-gather (bf16) ->
// out GEMM (+bias+residual, fp32 into d_out) -> LayerNorm in-place on d_out.
// fp32 accumulate everywhere. ws need = 142,741,952 B.
//
// R12: GEMM schedule frozen (R7/R9/R11 all 845-905 TF; with 128KB LDS = 1
// block/CU any barrier-locked schedule serializes LDS(2800cyc) + MFMA(2480cyc)
// per tile -- measured 5700 cyc/tile across three structurally distinct
// schedules; this is the plain-HIP structure ceiling). This round attacks the
// ~383us outside QKV:
//  - gf_kernel ELIMINATED: sum_{f=205..511} cos(2pi f d/1024) has the
//    Dirichlet closed form sin(307x)cos(716x)/sin(x), x=pi d/1024 (integer
//    mod-2048 angle reduction; d=0 -> 307). filter computes it per-block;
//    cbuf zeroing folded into cast_kernel.
//  - topk: 6x10 barrier tree (60 syncthreads) -> per-wave shfl_down argmax +
//    t0 merge (12 syncthreads), identical max/min-idx tie semantics.
//  - filter: 16 -> 64 blocks (256 thr), 4 CUs per batch.
//  - T1 bijective XCD swizzle on all 3 GEMM grids (768/256/256, all %8==0):
//    FETCH 151.7MB vs ~38MB unique read = cross-XCD A-strip re-fetch; chunked
//    swizzle fits each XCD's working set in its 4MB L2.

typedef unsigned short u16;
typedef unsigned int   u32;
typedef __attribute__((ext_vector_type(8))) __bf16 bf16x8;
typedef __attribute__((ext_vector_type(4))) float  floatx4;

#define HIDn 1024

__device__ __forceinline__ u16 f2b(float f){ u32 i = __float_as_uint(f); return (u16)((i + 0x7fffu + ((i>>16)&1u)) >> 16); }

__device__ __forceinline__ void gl_lds16(const u16* g, u16* l){
  __builtin_amdgcn_global_load_lds((__attribute__((address_space(1))) const void*)g,
                                   (__attribute__((address_space(3))) void*)l, 16, 0, 0);
}

__device__ __forceinline__ void bar(){
  asm volatile("" ::: "memory");
  __builtin_amdgcn_s_barrier();
  asm volatile("" ::: "memory");
}
__device__ __forceinline__ void lgkm0(){
  asm volatile("s_waitcnt lgkmcnt(0)" ::: "memory");
  __builtin_amdgcn_sched_barrier(0);
}

// ---------------------------------------------------------------- ws guard
__global__ void fill_kernel(float* __restrict__ out, float v, int n)
{
  const int i = blockIdx.x*blockDim.x + threadIdx.x;
  if (i < n) out[i] = v;
}

// ---------------------------------------------------------------- cast x -> bf16 (+zero cbuf)
__global__ __launch_bounds__(256)
void cast_kernel(const float* __restrict__ x, u16* __restrict__ xb,
                 float* __restrict__ cbuf)
{
  const int i = blockIdx.x*256 + threadIdx.x;   // 2,097,152 threads x 8 floats
  if (blockIdx.x < 64) cbuf[i] = 0.f;           // 16x1024 G-accumulator
  const float4* xp = (const float4*)x;
  const float4 a = xp[2*i], b = xp[2*i+1];
  uint4 o;
  o.x = (u32)f2b(a.x) | ((u32)f2b(a.y)<<16);
  o.y = (u32)f2b(a.z) | ((u32)f2b(a.w)<<16);
  o.z = (u32)f2b(b.x) | ((u32)f2b(b.y)<<16);
  o.w = (u32)f2b(b.z) | ((u32)f2b(b.w)<<16);
  ((uint4*)xb)[i] = o;
}

// ---------------------------------------------------------------- transpose+cast
// WqkvT (3072 x 1024, n-major, bf16) and WdT (1024 x 1024, bf16) from fp32 W.
__global__ __launch_bounds__(1024)
void transpose_kernel(const float* __restrict__ Wq, const float* __restrict__ Wk,
                      const float* __restrict__ Wv, const float* __restrict__ Wd,
                      u16* __restrict__ WqkvT, u16* __restrict__ WdT)
{
  __shared__ float tile[32][33];
  const int mat = blockIdx.z;
  const float* W = (mat==0)?Wq:(mat==1)?Wk:(mat==2)?Wv:Wd;
  const int k = blockIdx.y*32 + threadIdx.y;
  const int n = blockIdx.x*32 + threadIdx.x;
  tile[threadIdx.y][threadIdx.x] = W[(long)k*HIDn + n];
  __syncthreads();
  const int on = blockIdx.x*32 + threadIdx.y;
  const int ok = blockIdx.y*32 + threadIdx.x;
  const u16 val = f2b(tile[threadIdx.x][threadIdx.y]);
  if (mat < 3) WqkvT[(long)(mat*HIDn + on)*HIDn + ok] = val;
  else         WdT[(long)on*HIDn + ok] = val;
}

// ---------------------------------------------------------------- MFMA GEMM
// C(M x N) = A(M x K) * Bt(N x K)^T ; bf16 in, fp32 acc. 256x256 tile, 8 waves
// (2Mx4N), per-wave 128x64 (acc[8][4] 16x16x32 frags), BK=64, m201 8-phase
// schedule. Requires K % 128 == 0, K >= 256, grid size % 8 == 0 (T1 swizzle).
// EPI 0: +fp32 bias (select by bx>>2), bf16 split-store to C0/o1/o2 (Q/K/V).
// EPI 2: +fp32 bias +fp32 resid, fp32 out (hidden+residual -> d_out).
// EPI 3: no C store; diagonal-sum tile into cbuf[bz*1024 + d] (atomics).
template<int EPI>
__global__ __launch_bounds__(512, 2)
void gemm_mfma(const u16* __restrict__ A, int lda, long sA,
               const u16* __restrict__ Bt, int ldb, long sB,
               void* __restrict__ C0, u16* __restrict__ o1, u16* __restrict__ o2,
               int ldc, int K,
               const float* __restrict__ b0, const float* __restrict__ b1,
               const float* __restrict__ b2, const float* __restrict__ resid,
               float* __restrict__ cbuf)
{
  __shared__ __align__(16) u16 As[2][16384];   // 2 x (256 rows x 64 k)
  __shared__ __align__(16) u16 Bs[2][16384];
  __shared__ float bins[512];

  // T1: bijective XCD-chunk swizzle (grid % 8 == 0): each XCD gets a
  // contiguous chunk of the linearized grid -> A-strip reuse fits its L2.
  const int gx = gridDim.x, gy = gridDim.y;
  const int lin = (blockIdx.z*gy + blockIdx.y)*gx + blockIdx.x;
  const int cpx = (gx*gy*gridDim.z) >> 3;
  const int swz = (lin & 7)*cpx + (lin >> 3);
  const int bx  = swz % gx;
  const int byz = swz / gx;
  const int by  = byz % gy;
  const int bz  = byz / gy;

  const int tid  = threadIdx.x;
  const int wave = tid >> 6, lane = tid & 63;
  const int waveM = wave >> 2, waveN = wave & 3;
  const int qd = lane >> 4, ln = lane & 15, rl = ln & 7;
  const u16* Ab = A  + (long)bz * sA;
  const u16* Bb = Bt + (long)bz * sB;
  const int aRow0 = by * 256, bRow0 = bx * 256;
  const int nt = K >> 6;

  // staging: slot s = wave*128 + lane within a 128-row half (8 chunks/row)
  const int s0 = wave*128 + lane;
  const int r0 = s0 >> 3, r1 = r0 + 8;
  const int kc = ((s0 & 7) ^ (r0 & 7)) * 8;          // pre-swizzled source chunk
  const long aOff0 = (long)(aRow0 + r0)*lda + kc;
  const long aOff1 = (long)(aRow0 + r1)*lda + kc;
  const long bOff0 = (long)(bRow0 + r0)*ldb + kc;
  const long bOff1 = (long)(bRow0 + r1)*ldb + kc;
  const int dstW = wave*1024;                         // u16, wave-uniform

#define STAGE_A(p, h, kt) do{ \
    gl_lds16(Ab + aOff0 + (long)(h)*128*lda + (kt), &As[p][(h)*8192 + dstW]); \
    gl_lds16(Ab + aOff1 + (long)(h)*128*lda + (kt), &As[p][(h)*8192 + dstW + 512]); }while(0)
#define STAGE_B(p, h, kt) do{ \
    gl_lds16(Bb + bOff0 + (long)(h)*128*ldb + (kt), &Bs[p][(h)*8192 + dstW]); \
    gl_lds16(Bb + bOff1 + (long)(h)*128*ldb + (kt), &Bs[p][(h)*8192 + dstW + 512]); }while(0)

  if (EPI == 3) bins[tid] = 0.f;       // synced by prologue barrier

  floatx4 acc[8][4];
  const floatx4 z4 = {0.f, 0.f, 0.f, 0.f};
  #pragma unroll
  for (int i=0;i<8;++i)
    #pragma unroll
    for (int j=0;j<4;++j) acc[i][j] = z4;

  // read addressing: row R frag at u16 offset R*64 + ((chunk)^(R&7))*8
  const int aRd = (waveM*128 + ln)*64;   // + MH*4096 + mi*1024
  const int bRd = (waveN*64  + ln)*64;   // + ni*1024
  const int csw0 = ((0 + qd) ^ rl) * 8;  // kk=0 chunk
  const int csw1 = ((4 + qd) ^ rl) * 8;  // kk=1 chunk

  bf16x8 av0[4], av1[4];                 // current m-half, kk0/kk1
  bf16x8 bvA0[2], bvA1[2];               // n-half0 (ni 0,1), kk0/kk1
  bf16x8 bvB0[2], bvB1[2];               // n-half1 (ni 2,3), kk0/kk1

#define DS_AV(BUF, MH) do{ const u16* Ap_ = &As[BUF][0]; \
    _Pragma("unroll") for (int mi=0;mi<4;++mi){ \
      av0[mi] = *(const bf16x8*)(Ap_ + aRd + (MH)*4096 + mi*1024 + csw0); \
      av1[mi] = *(const bf16x8*)(Ap_ + aRd + (MH)*4096 + mi*1024 + csw1); } }while(0)
#define DS_BV(BUF, NH, d0_, d1_) do{ const u16* Bp_ = &Bs[BUF][0]; \
    _Pragma("unroll") for (int ni=0;ni<2;++ni){ \
      d0_[ni] = *(const bf16x8*)(Bp_ + bRd + ((NH)*2+ni)*1024 + csw0); \
      d1_[ni] = *(const bf16x8*)(Bp_ + bRd + ((NH)*2+ni)*1024 + csw1); } }while(0)
#define MFMAQ(MH, NH, b0_, b1_) do{ \
    __builtin_amdgcn_sched_barrier(0); \
    __builtin_amdgcn_s_setprio(1); \
    _Pragma("unroll") for (int mi=0;mi<4;++mi) \
      _Pragma("unroll") for (int ni=0;ni<2;++ni){ \
        acc[(MH)*4+mi][(NH)*2+ni] = __builtin_amdgcn_mfma_f32_16x16x32_bf16(av0[mi], b0_[ni], acc[(MH)*4+mi][(NH)*2+ni],0,0,0); \
        acc[(MH)*4+mi][(NH)*2+ni] = __builtin_amdgcn_mfma_f32_16x16x32_bf16(av1[mi], b1_[ni], acc[(MH)*4+mi][(NH)*2+ni],0,0,0); } \
    __builtin_amdgcn_s_setprio(0); \
    __builtin_amdgcn_sched_barrier(0); }while(0)

  // ---- prologue: stage tile0 -> buf0, tile1 -> buf1 (16 loads); tile0 landed
  STAGE_B(0,0,0);  STAGE_B(0,1,0);  STAGE_A(0,0,0);  STAGE_A(0,1,0);
  STAGE_B(1,0,64); STAGE_B(1,1,64); STAGE_A(1,0,64); STAGE_A(1,1,64);
  asm volatile("s_waitcnt vmcnt(8)" ::: "memory");
  bar();

  const int nIt = nt >> 1;
  for (int it = 0; it < nIt-1; ++it){
    const int k2 = (it*2+2) << 6;
    const int k3 = (it*2+3) << 6;
    // ======== tile t0 (buffer 0) ========
    // ph1 (m0,n0): 12 reads
    DS_AV(0,0); DS_BV(0,0,bvA0,bvA1);
    bar(); lgkm0(); MFMAQ(0,0,bvA0,bvA1); bar();
    // ph2 (m0,n1): 4 reads
    DS_BV(0,1,bvB0,bvB1);
    bar(); lgkm0(); MFMAQ(0,1,bvB0,bvB1); bar();
    // ph3 (m1,n0): 8 reads; stage B0(b0,t0+2) (B(b0) free since ph2-exit)
    DS_AV(0,1); STAGE_B(0,0,k2);
    bar(); lgkm0(); MFMAQ(1,0,bvA0,bvA1); bar();
    // ph4 (m1,n1): 0 reads; stage B1(b0); vmcnt(4) -> tile t1 fully landed
    STAGE_B(0,1,k2);
    asm volatile("s_waitcnt vmcnt(4)" ::: "memory");
    bar(); MFMAQ(1,1,bvB0,bvB1); bar();
    // ======== tile t1 (buffer 1) ========
    // ph5: stage A0(b0) (A(b0) free since ph3-exit)
    DS_AV(1,0); DS_BV(1,0,bvA0,bvA1); STAGE_A(0,0,k2);
    bar(); lgkm0(); MFMAQ(0,0,bvA0,bvA1); bar();
    // ph6: stage A1(b0)
    DS_BV(1,1,bvB0,bvB1); STAGE_A(0,1,k2);
    bar(); lgkm0(); MFMAQ(0,1,bvB0,bvB1); bar();
    // ph7: stage B0(b1,t1+2) (B(b1) free since ph6-exit)
    DS_AV(1,1); STAGE_B(1,0,k3);
    bar(); lgkm0(); MFMAQ(1,0,bvA0,bvA1); bar();
    // ph8: stage B1+A0+A1(b1) (A(b1) free since ph7-exit); vmcnt(8) -> b0 landed
    STAGE_B(1,1,k3); STAGE_A(1,0,k3); STAGE_A(1,1,k3);
    asm volatile("s_waitcnt vmcnt(8)" ::: "memory");
    bar(); MFMAQ(1,1,bvB0,bvB1); bar();
  }
  // ======== tail: tiles nt-2 (buf0), nt-1 (buf1), no stages ========
  DS_AV(0,0); DS_BV(0,0,bvA0,bvA1);
  bar(); lgkm0(); MFMAQ(0,0,bvA0,bvA1); bar();
  DS_BV(0,1,bvB0,bvB1);
  bar(); lgkm0(); MFMAQ(0,1,bvB0,bvB1); bar();
  DS_AV(0,1);
  bar(); lgkm0(); MFMAQ(1,0,bvA0,bvA1); bar();
  asm volatile("s_waitcnt vmcnt(0)" ::: "memory");  // drain b1 (tile nt-1)
  bar(); MFMAQ(1,1,bvB0,bvB1); bar();
  DS_AV(1,0); DS_BV(1,0,bvA0,bvA1);
  bar(); lgkm0(); MFMAQ(0,0,bvA0,bvA1); bar();
  DS_BV(1,1,bvB0,bvB1);
  bar(); lgkm0(); MFMAQ(0,1,bvB0,bvB1); bar();
  DS_AV(1,1);
  bar(); lgkm0(); MFMAQ(1,0,bvA0,bvA1); bar();
  MFMAQ(1,1,bvB0,bvB1);
#undef STAGE_A
#undef STAGE_B
#undef DS_AV
#undef DS_BV
#undef MFMAQ

  if (EPI == 3){
    // G[l][m] at frag(mi,ni) reg r lane(qd,ln):
    //   l-m = (aRow0-bRow0) + 128*waveM - 64*waveN + 16*(mi-ni) + 4*qd + r - ln
    float dsum[11][4];
    #pragma unroll
    for (int dd=0; dd<11; ++dd)
      #pragma unroll
      for (int r=0;r<4;++r) dsum[dd][r] = 0.f;
    #pragma unroll
    for (int mi=0;mi<8;++mi)
      #pragma unroll
      for (int ni=0;ni<4;++ni){
        const int dd = mi - ni + 3;
        #pragma unroll
        for (int r=0;r<4;++r) dsum[dd][r] += acc[mi][ni][r];
      }
    const int base = 255 + 128*waveM - 64*waveN + 4*qd - ln;
    #pragma unroll
    for (int dd=0; dd<11; ++dd)
      #pragma unroll
      for (int r=0;r<4;++r)
        atomicAdd(&bins[base + 16*(dd-3) + r], dsum[dd][r]);
    __syncthreads();
    if (tid < 511){
      const int d = (aRow0 - bRow0 + tid - 255) & 1023;
      atomicAdd(cbuf + bz*1024 + d, bins[tid]);
    }
    return;
  }

  // epilogue: C/D layout col = lane&15, row = (lane>>4)*4 + reg
  if (EPI == 0){
    const int which = bx >> 2;                 // 256-tile never crosses 1024
    const float* bp = (which==0) ? b0 : ((which==1) ? b1 : b2);
    u16* Cb = (which==0) ? (u16*)C0 : ((which==1) ? o1 : o2);
    const int nb = bRow0 & 1023;
    #pragma unroll
    for (int mi=0;mi<8;++mi){
      const int gm = aRow0 + waveM*128 + mi*16 + qd*4;
      #pragma unroll
      for (int ni=0;ni<4;++ni){
        const int nl = nb + waveN*64 + ni*16 + ln;
        const float bias = bp[nl];
        #pragma unroll
        for (int r=0;r<4;++r) Cb[(long)(gm+r)*ldc + nl] = f2b(acc[mi][ni][r] + bias);
      }
    }
  } else {  // EPI == 2
    float* C = (float*)C0;
    #pragma unroll
    for (int mi=0;mi<8;++mi){
      const int gm = aRow0 + waveM*128 + mi*16 + qd*4;
      #pragma unroll
      for (int ni=0;ni<4;++ni){
        const int gn = bRow0 + waveN*64 + ni*16 + ln;
        const float bias = b0[gn];
        #pragma unroll
        for (int r=0;r<4;++r)
          C[(long)(gm+r)*ldc + gn] = acc[mi][ni][r] + bias + resid[(long)(gm+r)*ldc + gn];
      }
    }
  }
}

// ---------------------------------------------------------------- filter
// mv[b,n] = sum_m c[b,m] * gf[(n-m)&1023], gf computed in closed form:
// sum_{f=205}^{511} cos(2 pi f d/1024) = sin(307x)cos(716x)/sin(x), x=pi d/1024
// (Dirichlet kernel; d=0 -> 307); gf[d] = (2*s + (-1)^d)/1024^2.
// grid 64: blockIdx = b*4 + quarter; 256 threads, one l each.
__global__ __launch_bounds__(256)
void filter_kernel(const float* __restrict__ c, float* __restrict__ mv)
{
  __shared__ float carr[1024];
  __shared__ float gsh[1024];
  const int b = blockIdx.x >> 2, l0 = (blockIdx.x & 3) << 8;
  const int t = threadIdx.x;
  #pragma unroll
  for (int j = 0; j < 4; ++j){
    const int d = t + j*256;
    carr[d] = c[b*1024 + d];
    float s;
    if (d == 0) s = 307.f;
    else {
      const float k = 3.14159265358979e0f/1024.f;
      const int n1 = (307*d) & 2047, n2 = (716*d) & 2047;   // angle mod 2pi
      s = sinf((float)n1*k) * cosf((float)n2*k) / sinf((float)d*k);
    }
    gsh[d] = (2.f*s + ((d & 1) ? -1.f : 1.f)) * (1.0f/1048576.0f);
  }
  __syncthreads();
  const int l = l0 + t;
  float o = 0.f;
  #pragma unroll 4
  for (int m = 0; m < 1024; ++m) o += carr[m] * gsh[(l - m) & 1023];
  mv[b*1024 + l] = o;
}

// ---------------------------------------------------------------- top-6 + softmax
// wave-shuffle argmax (value desc, index asc tiebreak -- associative, matches
// the old tree's semantics), 2 barriers per round vs the old 10.
__global__ __launch_bounds__(1024)
void topk_kernel(const float* __restrict__ mv, int* __restrict__ idxout,
                 float* __restrict__ wout)
{
  __shared__ float vals[1024];
  __shared__ float wv[16];
  __shared__ int   wi[16];
  __shared__ int   chosen[6];
  const int t = threadIdx.x, lane = t & 63, wid = t >> 6;
  float s = 0.f;
  #pragma unroll
  for (int b = 0; b < 16; ++b) s += mv[b*1024 + t];
  vals[t] = s;
  __syncthreads();
  for (int r = 0; r < 6; ++r){
    float cv = vals[t]; int ci = t;
    #pragma unroll
    for (int off = 32; off > 0; off >>= 1){
      const float ov = __shfl_down(cv, off);
      const int   oi = __shfl_down(ci, off);
      if (ov > cv || (ov == cv && oi < ci)){ cv = ov; ci = oi; }
    }
    if (lane == 0){ wv[wid] = cv; wi[wid] = ci; }
    __syncthreads();
    if (t == 0){
      float bv = wv[0]; int bi = wi[0];
      #pragma unroll
      for (int k = 1; k < 16; ++k)
        if (wv[k] > bv || (wv[k] == bv && wi[k] < bi)){ bv = wv[k]; bi = wi[k]; }
      chosen[r] = bi; idxout[r] = bi; vals[bi] = -3.0e38f;
    }
    __syncthreads();
  }
  if (t < 16){
    float w[6]; float mx = -3.0e38f;
    #pragma unroll
    for (int i = 0; i < 6; ++i){ w[i] = mv[t*1024 + chosen[i]]; mx = fmaxf(mx, w[i]); }
    float sum = 0.f;
    #pragma unroll
    for (int i = 0; i < 6; ++i){ w[i] = expf(w[i] - mx); sum += w[i]; }
    #pragma unroll
    for (int i = 0; i < 6; ++i) wout[t*6 + i] = w[i] / sum;
  }
}

// ---------------------------------------------------------------- context gather
// CT[b*1024+l, :] = sum_i w[b,i] * V[b, (l+idx_i)&1023, :]   (bf16 in/out)
__global__ __launch_bounds__(256)
void context_kernel(const u16* __restrict__ Vb, const int* __restrict__ idx,
                    const float* __restrict__ w, u16* __restrict__ CT)
{
  const int row = blockIdx.x*2 + (threadIdx.x >> 7);
  const int b = row >> 10, l = row & 1023;
  const int t = threadIdx.x & 127;       // chunk of 8 channels
  float wl[6]; int id[6];
  #pragma unroll
  for (int i = 0; i < 6; ++i){ id[i] = idx[i]; wl[i] = w[b*6 + i]; }
  float acc[8] = {0,0,0,0,0,0,0,0};
  #pragma unroll
  for (int i = 0; i < 6; ++i){
    const long src = (long)b*1024 + ((l + id[i]) & 1023);
    const uint4 pk = *(const uint4*)(Vb + src*1024 + t*8);
    const float ww = wl[i];
    union{float f; u32 u;} cv;
    cv.u = pk.x<<16;          acc[0] += ww*cv.f;
    cv.u = pk.x & 0xffff0000u; acc[1] += ww*cv.f;
    cv.u = pk.y<<16;          acc[2] += ww*cv.f;
    cv.u = pk.y & 0xffff0000u; acc[3] += ww*cv.f;
    cv.u = pk.z<<16;          acc[4] += ww*cv.f;
    cv.u = pk.z & 0xffff0000u; acc[5] += ww*cv.f;
    cv.u = pk.w<<16;          acc[6] += ww*cv.f;
    cv.u = pk.w & 0xffff0000u; acc[7] += ww*cv.f;
  }
  uint4 o;
  o.x = (u32)f2b(acc[0]) | ((u32)f2b(acc[1])<<16);
  o.y = (u32)f2b(acc[2]) | ((u32)f2b(acc[3])<<16);
  o.z = (u32)f2b(acc[4]) | ((u32)f2b(acc[5])<<16);
  o.w = (u32)f2b(acc[6]) | ((u32)f2b(acc[7])<<16);
  *(uint4*)(CT + (long)row*1024 + t*8) = o;
}

// ---------------------------------------------------------------- layernorm (in-place fp32)
__global__ __launch_bounds__(256)
void ln_kernel(float* __restrict__ io, const float* __restrict__ gamma,
               const float* __restrict__ beta)
{
  __shared__ float s1[256];
  __shared__ float s2[256];
  const int row = blockIdx.x, t = threadIdx.x;
  float4 v = ((const float4*)(io + (long)row*1024))[t];
  s1[t] = v.x+v.y+v.z+v.w;
  s2[t] = v.x*v.x+v.y*v.y+v.z*v.z+v.w*v.w;
  __syncthreads();
  for (int off = 128; off > 0; off >>= 1){
    if (t < off){ s1[t] += s1[t+off]; s2[t] += s2[t+off]; }
    __syncthreads();
  }
  const float mu  = s1[0] * (1.f/1024.f);
  const float var = fmaxf(s2[0] * (1.f/1024.f) - mu*mu, 0.f);
  const float rstd = rsqrtf(var + 1e-12f);
  const float4 g  = ((const float4*)gamma)[t];
  const float4 be = ((const float4*)beta)[t];
  float4 o;
  o.x = (v.x-mu)*rstd*g.x + be.x;
  o.y = (v.y-mu)*rstd*g.y + be.y;
  o.z = (v.z-mu)*rstd*g.z + be.z;
  o.w = (v.w-mu)*rstd*g.w + be.w;
  ((float4*)(io + (long)row*1024))[t] = o;
}

// ---------------------------------------------------------------- launch
extern "C" void kernel_launch(void* const* d_in, const int* in_sizes, int n_in,
                              void* d_out, int out_size, void* d_ws, size_t ws_size,
                              hipStream_t stream)
{
  (void)in_sizes; (void)n_in;
  const float* x     = (const float*)d_in[0];
  // d_in[1] attention_mask: zeros, unused by the reference math
  const float* Wq    = (const float*)d_in[2];
  const float* bq    = (const float*)d_in[3];
  const float* Wk    = (const float*)d_in[4];
  const float* bk    = (const float*)d_in[5];
  const float* Wv    = (const float*)d_in[6];
  const float* bv    = (const float*)d_in[7];
  const float* Wd    = (const float*)d_in[8];
  const float* bd    = (const float*)d_in[9];
  const float* gamma = (const float*)d_in[10];
  const float* beta  = (const float*)d_in[11];
  float* outp = (float*)d_out;

  // ws layout (bytes), total 142,741,952:
  // xb 32M | Qb 32M | Kb 32M | Vb 32M | WqkvT 6M | WdT 2M | cbuf 64K | mv 64K | (gf slot unused) | idx | w
  const size_t NEED = 142741952UL;
  if (ws_size < NEED){
    // guard: encode ws_size into the output so a failing absmax reveals it
    const int n = out_size/2;
    fill_kernel<<<(n+255)/256, 256, 0, stream>>>(outp, (float)ws_size, n);
    return;
  }
  char* ws = (char*)d_ws;
  u16*  xb    = (u16*)(ws);
  u16*  Qb    = (u16*)(ws + 33554432L);
  u16*  Kb    = (u16*)(ws + 67108864L);
  u16*  Vb    = (u16*)(ws + 100663296L);
  u16*  WqkvT = (u16*)(ws + 134217728L);
  u16*  WdT   = (u16*)(ws + 140509184L);
  float* cbuf = (float*)(ws + 142606336L);
  float* mv   = (float*)(ws + 142671872L);
  int*   idxb = (int*)  (ws + 142741504L);
  float* wsm  = (float*)(ws + 142741568L);
  u16*  CT    = Qb;   // reuse: Q's last reader is the G-gemm

  cast_kernel<<<8192, 256, 0, stream>>>(x, xb, cbuf);
  transpose_kernel<<<dim3(32,32,4), dim3(32,32), 0, stream>>>(Wq, Wk, Wv, Wd, WqkvT, WdT);

  // Q|K|V = x @ [Wq|Wk|Wv] + bias (M=16384, N=3072, K=1024), bf16 split-store
  gemm_mfma<0><<<dim3(12,64,1), 512, 0, stream>>>(
      xb, 1024, 0L, WqkvT, 1024, 0L, Qb, Kb, Vb, 1024, 1024,
      bq, bk, bv, nullptr, nullptr);

  // c[b,d] += diag-sums of Q[b] @ K[b]^T  (batched, M=N=K=1024, G not stored)
  gemm_mfma<3><<<dim3(4,4,16), 512, 0, stream>>>(
      Qb, 1024, 1048576L, Kb, 1024, 1048576L, nullptr, nullptr, nullptr, 0, 1024,
      nullptr, nullptr, nullptr, nullptr, cbuf);

  filter_kernel<<<64, 256, 0, stream>>>(cbuf, mv);
  topk_kernel<<<1, 1024, 0, stream>>>(mv, idxb, wsm);
  context_kernel<<<8192, 256, 0, stream>>>(Vb, idxb, wsm, CT);

  // d_out = CT @ Wd + bd + x  (fp32, M=16384, N=1024, K=1024)
  gemm_mfma<2><<<dim3(4,64,1), 512, 0, stream>>>(
      CT, 1024, 0L, WdT, 1024, 0L, outp, nullptr, nullptr, 1024, 1024,
      bd, nullptr, nullptr, x, nullptr);

  ln_kernel<<<16384, 256, 0, stream>>>(outp, gamma, beta);
}